// Round 18
// baseline (280.473 us; speedup 1.0000x reference)
//
#include <hip/hip_runtime.h>

// UserGraphNet: B=64 graphs, n=714 nodes, E=16384 edges (+n self loops), C=128.
// Round 17: eighth-wave aggregation — 8 nodes/wave (8-lane eighth per node),
// each lane owns 16 channels (2x f16x8 per edge), single acc[16] set (2 edges
// in flight share it) to stay under the 64-VGPR occupancy cliff. Wave count
// halves again (round-11/16 gradient). Rest as round 16: split structure,
// f16 features, 2-term MFMA GEMMs, merged build+prep, projection embed,
// fused W_out dot, XCD swizzle.

#define BB 64
#define NN 714
#define EE 16384
#define ET (EE + NN)          // 17098 edges incl self loops
#define NBt (BB * NN)         // 45696 total nodes
#define CC 128
#define RP (NN + 1)           // rowptr entries per graph
#define DFAST 64              // max degree on the eighth-wave fast path (deg~24)
#define KSP 28                // total padded k-steps across 4 table projections
#define PROJ_ROWS 19021       // 5099 + 400 + 7128 + 6394

typedef _Float16 f16;
typedef __attribute__((ext_vector_type(8))) _Float16 f16x8;
typedef __attribute__((ext_vector_type(4))) _Float16 f16x4;
typedef __attribute__((ext_vector_type(4))) float f32x4;

__device__ __forceinline__ float lrelu01(float x) { return x > 0.f ? x : 0.01f * x; }
__device__ __forceinline__ float lrelu2(float x)  { return x > 0.f ? x : 0.2f  * x; }

__device__ __forceinline__ float wsum(float x) {
#pragma unroll
    for (int o = 32; o > 0; o >>= 1) x += __shfl_xor(x, o);
    return x;
}
// 16-lane (quarter-wave) reductions
__device__ __forceinline__ float qsum(float x) {
#pragma unroll
    for (int o = 8; o > 0; o >>= 1) x += __shfl_xor(x, o);
    return x;
}
// 8-lane (eighth-wave) reductions: xor offsets <=4 stay within the eighth
__device__ __forceinline__ float esum(float x) {
#pragma unroll
    for (int o = 4; o > 0; o >>= 1) x += __shfl_xor(x, o);
    return x;
}
__device__ __forceinline__ float emax(float x) {
#pragma unroll
    for (int o = 4; o > 0; o >>= 1) x = fmaxf(x, __shfl_xor(x, o));
    return x;
}

// Bijective XCD swizzle (m204)
__device__ __forceinline__ int xcd_swz(int bid, int nwg) {
    int q = nwg >> 3, r = nwg & 7;
    int x = bid & 7, l = bid >> 3;
    int base = (x < r) ? x * (q + 1) : r * (q + 1) + (x - r) * q;
    return base + l;
}

// ---- merged CSR build (blocks 0..BB-1) + weight prep (blocks BB..) ----
#define NSEG (KSP * 8 * 64)
#define NGAT (3 * 4 * 8 * 64)
#define NPREP (NSEG + NGAT + 3 * CC)
__global__ __launch_bounds__(1024) void k_build_prep(
    const int* __restrict__ edges, int* __restrict__ rowptr,
    int* __restrict__ csr_row, float* __restrict__ dinv,
    const float* __restrict__ W, const float* __restrict__ gat_W,
    const float* __restrict__ a_s, const float* __restrict__ a_d,
    f16* __restrict__ BWh, f16* __restrict__ BWl,
    f16* __restrict__ BGh, f16* __restrict__ BGl,
    float* __restrict__ wsv, float* __restrict__ wdv) {
    __shared__ int degs[NN];
    __shared__ int scan[1024];
    __shared__ int curs[NN];
    int t = threadIdx.x;
    if (blockIdx.x < BB) {
        // ---------------- CSR build ----------------
        int b = blockIdx.x;
        if (t < NN) degs[t] = 0;
        __syncthreads();
        int rr[17], cc[17];
#pragma unroll
        for (int q = 0; q < 17; ++q) {
            int e = q * 1024 + t;
            int r = -1, c = -1;
            if (e < ET) {
                if (e < EE) { r = edges[b * 2 * EE + e]; c = edges[b * 2 * EE + EE + e]; }
                else        { r = c = e - EE; }
                atomicAdd(&degs[c], 1);
            }
            rr[q] = r; cc[q] = c;
        }
        __syncthreads();
        int cnt = (t < NN) ? degs[t] : 0;
        scan[t] = cnt;
        __syncthreads();
        for (int off = 1; off < 1024; off <<= 1) {
            int val = (t >= off) ? scan[t - off] : 0;
            __syncthreads();
            scan[t] += val;
            __syncthreads();
        }
        if (t < NN) {
            rowptr[b * RP + t + 1] = scan[t];
            curs[t] = scan[t] - cnt;                   // exclusive prefix
            dinv[b * NN + t] = cnt > 0 ? rsqrtf((float)cnt) : 0.f;
        }
        if (t == 0) rowptr[b * RP] = 0;
        __syncthreads();
#pragma unroll
        for (int q = 0; q < 17; ++q) {
            if (cc[q] >= 0) {
                int slot = atomicAdd(&curs[cc[q]], 1); // LDS atomic
                csr_row[b * ET + slot] = rr[q];
            }
        }
        return;
    }
    // ---------------- weight prep ----------------
    int idx = (blockIdx.x - BB) * 1024 + t;
    if (idx < NSEG) {
        int lane = idx & 63, tc = idx >> 6;
        int ct = tc & 7, ks = tc >> 3;
        int tt = ks < 10 ? 0 : ks < 14 ? 1 : ks < 21 ? 2 : 3;
        int k0 = tt == 0 ? 0 : tt == 1 ? 10 : tt == 2 ? 14 : 21;
        const int Ktab[4] = {300, 100, 200, 200};
        const int Koff[4] = {0, 300, 400, 600};
        int ksl = ks - k0;
        f16x8 ph, pl;
#pragma unroll
        for (int j = 0; j < 8; ++j) {
            int k = ksl * 32 + (lane >> 4) * 8 + j;
            int c = ct * 16 + (lane & 15);
            float v = (k < Ktab[tt]) ? W[(size_t)(Koff[tt] + k) * CC + c] : 0.f;
            f16 hi = (f16)v;
            ph[j] = hi; pl[j] = (f16)(v - (float)hi);
        }
        *(f16x8*)(BWh + (size_t)idx * 8) = ph;
        *(f16x8*)(BWl + (size_t)idx * 8) = pl;
    } else if (idx < NSEG + NGAT) {
        int i2 = idx - NSEG;
        int lane = i2 & 63, tc = i2 >> 6;
        int ct = tc & 7; tc >>= 3;
        int ks = tc & 3, li = tc >> 2;
        const float* Wl = gat_W + (size_t)li * CC * CC;
        f16x8 ph, pl;
#pragma unroll
        for (int j = 0; j < 8; ++j) {
            int k = ks * 32 + (lane >> 4) * 8 + j;
            int c = ct * 16 + (lane & 15);
            float v = Wl[k * CC + c];
            f16 hi = (f16)v;
            ph[j] = hi; pl[j] = (f16)(v - (float)hi);
        }
        *(f16x8*)(BGh + (size_t)i2 * 8) = ph;
        *(f16x8*)(BGl + (size_t)i2 * 8) = pl;
    } else if (idx < NPREP) {
        int i2 = idx - NSEG - NGAT;
        int i = i2 >> 7, k = i2 & 127;
        const float* Wl = gat_W + (size_t)i * CC * CC;
        float s = 0.f, d = 0.f;
#pragma unroll 4
        for (int c = 0; c < CC; ++c) {
            float w = Wl[k * CC + c];
            s = fmaf(w, a_s[i * CC + c], s);
            d = fmaf(w, a_d[i * CC + c], d);
        }
        wsv[i * CC + k] = s; wdv[i * CC + k] = d;
    }
}

// ---- table-projection GEMM: P[t] = table[t] @ W_in[Koff:Koff+K]  (f32 out) ----
__global__ __launch_bounds__(256) void k_proj(
    const float* __restrict__ poi, const float* __restrict__ cat,
    const float* __restrict__ lat, const float* __restrict__ lon,
    const f16* __restrict__ Bh, const f16* __restrict__ Bl,
    float* __restrict__ P) {
    int bid = blockIdx.x;
    int t, r0;
    if (bid < 160)      { t = 0; r0 = bid * 32; }
    else if (bid < 173) { t = 1; r0 = (bid - 160) * 32; }
    else if (bid < 396) { t = 2; r0 = (bid - 173) * 32; }
    else                { t = 3; r0 = (bid - 396) * 32; }
    const int Ktab[4] = {300, 100, 200, 200};
    const int Rtab[4] = {5099, 400, 7128, 6394};
    const int Rofs[4] = {0, 5099, 5499, 12627};
    const int Kst[4]  = {10, 4, 7, 7};
    const int Bks0[4] = {0, 10, 14, 21};
    const float* tab = t == 0 ? poi : t == 1 ? cat : t == 2 ? lat : lon;
    int K = Ktab[t], R = Rtab[t], nks = Kst[t], bks = Bks0[t];
    int lane = threadIdx.x & 63, w = threadIdx.x >> 6;
    int ct0 = w * 2;
    f32x4 acc[2][2];
#pragma unroll
    for (int rt = 0; rt < 2; ++rt)
#pragma unroll
        for (int c = 0; c < 2; ++c) acc[rt][c] = (f32x4){0.f, 0.f, 0.f, 0.f};

    for (int ks = 0; ks < nks; ++ks) {
        int kbase = ks * 32 + (lane >> 4) * 8;
        f16x8 ah[2], al[2];
#pragma unroll
        for (int rt = 0; rt < 2; ++rt) {
            int row = r0 + rt * 16 + (lane & 15);
            int rowc = row < R ? row : R - 1;
            const float* rp = tab + (size_t)rowc * K;
            float v[8];
            if (kbase + 8 <= K) {
                float4 x0 = ((const float4*)(rp + kbase))[0];
                float4 x1 = ((const float4*)(rp + kbase))[1];
                v[0] = x0.x; v[1] = x0.y; v[2] = x0.z; v[3] = x0.w;
                v[4] = x1.x; v[5] = x1.y; v[6] = x1.z; v[7] = x1.w;
            } else if (kbase >= K) {
#pragma unroll
                for (int m = 0; m < 8; ++m) v[m] = 0.f;
            } else {
#pragma unroll
                for (int m = 0; m < 8; ++m) v[m] = (kbase + m < K) ? rp[kbase + m] : 0.f;
            }
#pragma unroll
            for (int j = 0; j < 8; ++j) {
                f16 hi = (f16)v[j];
                ah[rt][j] = hi; al[rt][j] = (f16)(v[j] - (float)hi);
            }
        }
#pragma unroll
        for (int cti = 0; cti < 2; ++cti) {
            int ct = ct0 + cti;
            f16x8 bh = *(const f16x8*)(Bh + ((size_t)((bks + ks) * 8 + ct) * 64 + lane) * 8);
            f16x8 bl = *(const f16x8*)(Bl + ((size_t)((bks + ks) * 8 + ct) * 64 + lane) * 8);
#pragma unroll
            for (int rt = 0; rt < 2; ++rt) {
                acc[rt][cti] = __builtin_amdgcn_mfma_f32_16x16x32_f16(ah[rt], bh, acc[rt][cti], 0, 0, 0);
                acc[rt][cti] = __builtin_amdgcn_mfma_f32_16x16x32_f16(al[rt], bh, acc[rt][cti], 0, 0, 0);
                acc[rt][cti] = __builtin_amdgcn_mfma_f32_16x16x32_f16(ah[rt], bl, acc[rt][cti], 0, 0, 0);
            }
        }
    }
#pragma unroll
    for (int rt = 0; rt < 2; ++rt)
#pragma unroll
        for (int cti = 0; cti < 2; ++cti)
#pragma unroll
            for (int i = 0; i < 4; ++i) {
                int row = r0 + rt * 16 + (lane >> 4) * 4 + i;
                if (row < R) {
                    int col = (ct0 + cti) * 16 + (lane & 15);
                    P[(size_t)(Rofs[t] + row) * CC + col] = acc[rt][cti][i];
                }
            }
}

// ---- per-node assembly: bufB[g] = P_poi[f0] + P_cat[f1] + P_lat[f3] + P_lon[f4] ----
__global__ __launch_bounds__(256) void k_assemble(
    const int* __restrict__ feature, const float* __restrict__ P,
    f16* __restrict__ out) {
    int tid = xcd_swz(blockIdx.x, gridDim.x) * 256 + threadIdx.x;
    int g = tid >> 4, c8 = (tid & 15) * 8;
    const int* f = feature + (size_t)g * 5;
    const float4* p0 = (const float4*)(P + (size_t)f[0] * CC + c8);
    const float4* p1 = (const float4*)(P + (size_t)(5099 + f[1]) * CC + c8);
    const float4* p2 = (const float4*)(P + (size_t)(5499 + f[3]) * CC + c8);
    const float4* p3 = (const float4*)(P + (size_t)(12627 + f[4]) * CC + c8);
    float4 a0 = p0[0], a1 = p0[1];
    float4 b0 = p1[0], b1 = p1[1];
    float4 c0 = p2[0], c1 = p2[1];
    float4 d0 = p3[0], d1 = p3[1];
    f16x8 r;
    r[0] = (f16)(a0.x + b0.x + c0.x + d0.x);
    r[1] = (f16)(a0.y + b0.y + c0.y + d0.y);
    r[2] = (f16)(a0.z + b0.z + c0.z + d0.z);
    r[3] = (f16)(a0.w + b0.w + c0.w + d0.w);
    r[4] = (f16)(a1.x + b1.x + c1.x + d1.x);
    r[5] = (f16)(a1.y + b1.y + c1.y + d1.y);
    r[6] = (f16)(a1.z + b1.z + c1.z + d1.z);
    r[7] = (f16)(a1.w + b1.w + c1.w + d1.w);
    *(f16x8*)(out + (size_t)g * CC + c8) = r;
}

// ---- GAT gemm, 32-row tile; f16 input (exact A, 2-term MFMA); f16 Hp out ----
__global__ __launch_bounds__(256) void k_gat_gemm(
    const f16* __restrict__ hin, const f16* __restrict__ Bh, const f16* __restrict__ Bl,
    const float* __restrict__ wsv, const float* __restrict__ wdv,
    f16* __restrict__ Hp, float* __restrict__ asrc, float* __restrict__ adst) {
    __shared__ __align__(16) f16 Ah[32 * 128];
    __shared__ float reds[256], redd[256];
    int t = threadIdx.x;
    int g0 = xcd_swz(blockIdx.x, gridDim.x) * 32;
    int lane = t & 63, w = t >> 6;
    int sr = t >> 3, skb = (t & 7) * 16;
    const f16x8* hrow = (const f16x8*)(hin + (size_t)(g0 + sr) * CC + skb);
    f16x8 hv0 = hrow[0], hv1 = hrow[1];
    float ps = 0.f, pd = 0.f;
#pragma unroll
    for (int m = 0; m < 8; ++m) {
        ps = fmaf((float)hv0[m], wsv[skb + m], ps);
        pd = fmaf((float)hv0[m], wdv[skb + m], pd);
        ps = fmaf((float)hv1[m], wsv[skb + 8 + m], ps);
        pd = fmaf((float)hv1[m], wdv[skb + 8 + m], pd);
    }
    {
        int kg0 = (t & 7) * 2;
        int ad0 = sr * 128 + ((kg0 ^ (sr & 7)) << 3);
        int ad1 = sr * 128 + (((kg0 + 1) ^ (sr & 7)) << 3);
        *(f16x8*)&Ah[ad0] = hv0;
        *(f16x8*)&Ah[ad1] = hv1;
    }
    reds[t] = ps; redd[t] = pd;
    __syncthreads();
    if (t < 32) {
        float s = 0.f, d = 0.f;
#pragma unroll
        for (int q = 0; q < 8; ++q) { s += reds[t * 8 + q]; d += redd[t * 8 + q]; }
        asrc[g0 + t] = s; adst[g0 + t] = d;
    }
    f32x4 acc[2][2];
#pragma unroll
    for (int rt = 0; rt < 2; ++rt)
#pragma unroll
        for (int c = 0; c < 2; ++c) acc[rt][c] = (f32x4){0.f, 0.f, 0.f, 0.f};
    int ct0 = w * 2;
#pragma unroll
    for (int ks = 0; ks < 4; ++ks) {
        f16x8 ahf[2];
#pragma unroll
        for (int rt = 0; rt < 2; ++rt) {
            int r = rt * 16 + (lane & 15);
            int kg = (lane >> 4) + ks * 4;
            int ad = r * 128 + ((kg ^ (r & 7)) << 3);
            ahf[rt] = *(const f16x8*)&Ah[ad];
        }
#pragma unroll
        for (int cti = 0; cti < 2; ++cti) {
            int ct = ct0 + cti;
            f16x8 bh = *(const f16x8*)(Bh + ((size_t)(ks * 8 + ct) * 64 + lane) * 8);
            f16x8 bl = *(const f16x8*)(Bl + ((size_t)(ks * 8 + ct) * 64 + lane) * 8);
#pragma unroll
            for (int rt = 0; rt < 2; ++rt) {
                acc[rt][cti] = __builtin_amdgcn_mfma_f32_16x16x32_f16(ahf[rt], bh, acc[rt][cti], 0, 0, 0);
                acc[rt][cti] = __builtin_amdgcn_mfma_f32_16x16x32_f16(ahf[rt], bl, acc[rt][cti], 0, 0, 0);
            }
        }
    }
#pragma unroll
    for (int rt = 0; rt < 2; ++rt)
#pragma unroll
        for (int cti = 0; cti < 2; ++cti)
#pragma unroll
            for (int i = 0; i < 4; ++i) {
                int row = g0 + rt * 16 + (lane >> 4) * 4 + i;
                int col = (ct0 + cti) * 16 + (lane & 15);
                Hp[(size_t)row * CC + col] = (f16)acc[rt][cti][i];
            }
}

// ---- unified aggregate kernel: 8 nodes per wave (8-lane eighth per node) ----
// Each lane owns 16 channels (2x f16x8 per edge); single acc[16] shared by the
// 2 edges in flight. MODE 0: GAT res; MODE 1: GAT; MODE 2: GCN; MODE 3: GAT+dot.
template <int MODE>
__global__ __launch_bounds__(256) void k_agg(
    const f16* __restrict__ Hp, const float* __restrict__ aux,
    const float* __restrict__ adst, const int* __restrict__ rowptr,
    const int* __restrict__ csr_row, const float* __restrict__ bias,
    f16* __restrict__ out, const float* __restrict__ Wout, float* __restrict__ pscal) {
    __shared__ float2 pr[4][8][DFAST + 2];   // +2 pad: eighths land in distinct banks
    int wid = threadIdx.x >> 6, lane = threadIdx.x & 63;
    int eighth = lane >> 3, el = lane & 7;
    int g = xcd_swz(blockIdx.x, gridDim.x) * 32 + wid * 8 + eighth;
    int b = g / NN, v = g - b * NN;
    int bN = b * NN, bE = b * ET;
    int s0 = rowptr[b * RP + v], s1 = rowptr[b * RP + v + 1];
    int deg = s1 - s0;

    if (deg <= DFAST) {
        int degp = (deg + 1) & ~1;                 // pad to multiple of 2
        float inv = 1.f;
        // ---- phase 1: <=8 edges/lane in registers, eighth reductions ----
        if (MODE == 2) {
            float dv = aux[g];
#pragma unroll
            for (int u = 0; u < 8; ++u) {
                int jj = el + u * 8;
                int r = 0; float w = 0.f;
                if (jj < deg) { r = csr_row[bE + s0 + jj]; w = aux[bN + r] * dv; }
                if (jj < degp) pr[wid][eighth][jj] = make_float2(w, __int_as_float(r));
            }
        } else {
            float adv = adst[g];
            float ev[8];
            int rv[8];
#pragma unroll
            for (int u = 0; u < 8; ++u) {
                int jj = el + u * 8;
                rv[u] = 0; ev[u] = -3.0e38f;
                if (jj < deg) { rv[u] = csr_row[bE + s0 + jj]; ev[u] = lrelu2(aux[bN + rv[u]] + adv); }
            }
            float mloc = ev[0];
#pragma unroll
            for (int u = 1; u < 8; ++u) mloc = fmaxf(mloc, ev[u]);
            float m = emax(mloc);
            float ss = 0.f;
#pragma unroll
            for (int u = 0; u < 8; ++u) {
                float w = __expf(ev[u] - m);        // pads: exp(-inf)=0
                ss += w;
                int jj = el + u * 8;
                if (jj < degp) pr[wid][eighth][jj] = make_float2(w, __int_as_float(rv[u]));
            }
            ss = esum(ss);
            inv = 1.f / (ss + 1e-16f);              // applied once at the end
        }
        // DS pipe is in-order per wave: phase-2 reads see this wave's writes.
        // ---- phase 2: 2 edges/iter, 2x f16x8 per edge per lane, acc lane-local ----
        const f16* Hb = Hp + (size_t)bN * CC;
        float acc[16];
#pragma unroll
        for (int j = 0; j < 16; ++j) acc[j] = 0.f;
        for (int jj = 0; jj < degp; jj += 2) {
            float2 p0 = pr[wid][eighth][jj];
            float2 p1 = pr[wid][eighth][jj + 1];
            const f16* r0p = Hb + (size_t)__float_as_int(p0.y) * CC + el * 16;
            const f16* r1p = Hb + (size_t)__float_as_int(p1.y) * CC + el * 16;
            f16x8 a0 = ((const f16x8*)r0p)[0];
            f16x8 a1 = ((const f16x8*)r0p)[1];
            f16x8 b0 = ((const f16x8*)r1p)[0];
            f16x8 b1 = ((const f16x8*)r1p)[1];
#pragma unroll
            for (int j = 0; j < 8; ++j) {
                acc[j]     = fmaf((float)a0[j], p0.x, acc[j]);
                acc[8 + j] = fmaf((float)a1[j], p0.x, acc[8 + j]);
                acc[j]     = fmaf((float)b0[j], p1.x, acc[j]);
                acc[8 + j] = fmaf((float)b1[j], p1.x, acc[8 + j]);
            }
        }
        // ---- epilogue: all 8 lanes live, acc lane-local (16 channels) ----
        float sc = (MODE == 2) ? 1.f : inv;
        float ov[16];
#pragma unroll
        for (int q = 0; q < 4; ++q) {
            float4 bb = ((const float4*)bias)[el * 4 + q];
#pragma unroll
            for (int k = 0; k < 4; ++k) {
                int j = q * 4 + k;
                float tv = acc[j] * sc + ((const float*)&bb)[k];
                float l = lrelu01(tv);
                ov[j] = (MODE == 0) ? l + tv : l;
            }
        }
        if (MODE == 3) {
            // fused out_dot: pscal[g] = ov . Wout
            float p = 0.f;
#pragma unroll
            for (int q = 0; q < 4; ++q) {
                float4 wv = ((const float4*)Wout)[el * 4 + q];
#pragma unroll
                for (int k = 0; k < 4; ++k)
                    p = fmaf(ov[q * 4 + k], ((const float*)&wv)[k], p);
            }
            p = esum(p);
            if (el == 0) pscal[g] = p;
        } else {
            f16x8 r0, r1;
#pragma unroll
            for (int j = 0; j < 8; ++j) { r0[j] = (f16)ov[j]; r1[j] = (f16)ov[8 + j]; }
            f16* op = out + (size_t)g * CC + el * 16;
            ((f16x8*)op)[0] = r0;
            ((f16x8*)op)[1] = r1;
        }
        return;
    }
    // ---- fallback deg > DFAST: eighth-wave serial loop; ~never taken ----
    {
        float wsc0 = 0.f;
        float m = 0.f, inv = 1.f, adv = 0.f;
        if (MODE != 2) {
            adv = adst[g];
            m = -3.0e38f;
            for (int j = s0 + el; j < s1; j += 8)
                m = fmaxf(m, lrelu2(aux[bN + csr_row[bE + j]] + adv));
            m = emax(m);
            float ssum = 0.f;
            for (int j = s0 + el; j < s1; j += 8)
                ssum += __expf(lrelu2(aux[bN + csr_row[bE + j]] + adv) - m);
            ssum = esum(ssum);
            inv = 1.f / (ssum + 1e-16f);
        } else {
            wsc0 = aux[g];
        }
        float acc[16];
#pragma unroll
        for (int j = 0; j < 16; ++j) acc[j] = 0.f;
        for (int j = s0; j < s1; ++j) {
            int r = csr_row[bE + j];
            float wj = (MODE == 2) ? aux[bN + r]
                                   : __expf(lrelu2(aux[bN + r] + adv) - m) * inv;
            const f16* rp = Hp + (size_t)(bN + r) * CC + el * 16;
            f16x8 h0 = ((const f16x8*)rp)[0];
            f16x8 h1 = ((const f16x8*)rp)[1];
#pragma unroll
            for (int k = 0; k < 8; ++k) {
                acc[k]     = fmaf(wj, (float)h0[k], acc[k]);
                acc[8 + k] = fmaf(wj, (float)h1[k], acc[8 + k]);
            }
        }
        if (MODE == 2) {
#pragma unroll
            for (int k = 0; k < 16; ++k) acc[k] *= wsc0;
        }
        float ov[16];
#pragma unroll
        for (int q = 0; q < 4; ++q) {
            float4 bb = ((const float4*)bias)[el * 4 + q];
#pragma unroll
            for (int k = 0; k < 4; ++k) {
                int j = q * 4 + k;
                float tv = acc[j] + ((const float*)&bb)[k];
                float l = lrelu01(tv);
                ov[j] = (MODE == 0) ? l + tv : l;
            }
        }
        if (MODE == 3) {
            float p = 0.f;
#pragma unroll
            for (int q = 0; q < 4; ++q) {
                float4 wv = ((const float4*)Wout)[el * 4 + q];
#pragma unroll
                for (int k = 0; k < 4; ++k)
                    p = fmaf(ov[q * 4 + k], ((const float*)&wv)[k], p);
            }
            p = esum(p);
            if (el == 0) pscal[g] = p;
        } else {
            f16x8 r0, r1;
#pragma unroll
            for (int j = 0; j < 8; ++j) { r0[j] = (f16)ov[j]; r1[j] = (f16)ov[8 + j]; }
            f16* op = out + (size_t)g * CC + el * 16;
            ((f16x8*)op)[0] = r0;
            ((f16x8*)op)[1] = r1;
        }
    }
}

// ---- GCN2 aggregate over scalars: 4 nodes/wave, 16 lanes per node ----
__global__ __launch_bounds__(256) void k_out_agg(
    const float* __restrict__ p, const float* __restrict__ dinv,
    const int* __restrict__ rowptr, const int* __restrict__ csr_row,
    const float* __restrict__ bout, float* __restrict__ gv) {
    int wid = threadIdx.x >> 6, lane = threadIdx.x & 63;
    int quarter = lane >> 4, ql = lane & 15;
    int g = xcd_swz(blockIdx.x, gridDim.x) * 16 + wid * 4 + quarter;
    int b = g / NN, v = g - b * NN;
    int s0 = rowptr[b * RP + v], s1 = rowptr[b * RP + v + 1];
    float acc = 0.f;
    for (int j = s0 + ql; j < s1; j += 16) {
        int r = csr_row[b * ET + j];
        acc += dinv[b * NN + r] * p[b * NN + r];
    }
    acc = qsum(acc);
    if (ql == 0) gv[g] = lrelu01(acc * dinv[g] + bout[0]);
}

__global__ __launch_bounds__(128) void k_fc(
    const float* __restrict__ gv, const float* __restrict__ W1,
    const float* __restrict__ b1, const float* __restrict__ W2,
    const float* __restrict__ b2, float* __restrict__ outp) {
    __shared__ float gs[NN];
    __shared__ float s1[CC];
    int b = blockIdx.x, tx = threadIdx.x;
    for (int v = tx; v < NN; v += 128) gs[v] = gv[b * NN + v];
    __syncthreads();
    float acc = 0.f;
    for (int v = 0; v < NN; ++v) acc = fmaf(gs[v], W1[v * CC + tx], acc);
    float t = lrelu01(acc + b1[tx]);
    s1[tx] = t;
    __syncthreads();
    float acc2 = 0.f;
#pragma unroll
    for (int k = 0; k < CC; ++k) acc2 = fmaf(s1[k], W2[k * CC + tx], acc2);
    outp[b * CC + tx] = acc2 + b2[tx];
}

extern "C" void kernel_launch(void* const* d_in, const int* in_sizes, int n_in,
                              void* d_out, int out_size, void* d_ws, size_t ws_size,
                              hipStream_t stream) {
    const int*   feature  = (const int*)d_in[0];
    const int*   edges    = (const int*)d_in[1];
    const float* poi      = (const float*)d_in[3];
    const float* cat      = (const float*)d_in[4];
    const float* lat      = (const float*)d_in[5];
    const float* lon      = (const float*)d_in[6];
    const float* W_in     = (const float*)d_in[7];
    const float* b_in     = (const float*)d_in[8];
    const float* gat_W    = (const float*)d_in[9];
    const float* gat_asrc = (const float*)d_in[10];
    const float* gat_adst = (const float*)d_in[11];
    const float* gat_b    = (const float*)d_in[12];
    const float* W_out    = (const float*)d_in[13];
    const float* b_out    = (const float*)d_in[14];
    const float* W_fc1    = (const float*)d_in[15];
    const float* b_fc1    = (const float*)d_in[16];
    const float* W_fc2    = (const float*)d_in[17];
    const float* b_fc2    = (const float*)d_in[18];
    float* outp = (float*)d_out;

    char* ws = (char*)d_ws;
    size_t off = 0;
    auto take = [&](size_t bytes) -> char* {
        char* pp = ws + off;
        off = (off + bytes + 255) & ~(size_t)255;
        return pp;
    };
    int*   csr    = (int*)take((size_t)BB * ET * 4);
    int*   rowptr = (int*)take((size_t)BB * RP * 4);
    float* dinv   = (float*)take((size_t)NBt * 4);
    float* asrc   = (float*)take((size_t)NBt * 4);
    float* adst   = (float*)take((size_t)NBt * 4);
    float* pscal  = (float*)take((size_t)NBt * 4);
    float* gvec   = (float*)take((size_t)NBt * 4);
    f16*   bufA   = (f16*)take((size_t)NBt * CC * 2);       // f16 node features
    f16*   bufB   = (f16*)take((size_t)NBt * CC * 2);       // f16 node features
    float* P      = (float*)take((size_t)PROJ_ROWS * CC * 4); // table projections
    f16*   BWh    = (f16*)take((size_t)KSP * 8 * 64 * 8 * 2);
    f16*   BWl    = (f16*)take((size_t)KSP * 8 * 64 * 8 * 2);
    f16*   BGh    = (f16*)take((size_t)3 * 4 * 8 * 64 * 8 * 2);
    f16*   BGl    = (f16*)take((size_t)3 * 4 * 8 * 64 * 8 * 2);
    float* wsv    = (float*)take((size_t)3 * CC * 4);
    float* wdv    = (float*)take((size_t)3 * CC * 4);

    // merged CSR build + weight prep: blocks [0,BB) build, [BB, BB+21) prep
    const int prep_blocks = (NPREP + 1023) / 1024;
    k_build_prep<<<BB + prep_blocks, 1024, 0, stream>>>(
        edges, rowptr, csr, dinv,
        W_in, gat_W, gat_asrc, gat_adst, BWh, BWl, BGh, BGl, wsv, wdv);

    k_proj<<<596, 256, 0, stream>>>(poi, cat, lat, lon, BWh, BWl, P);
    k_assemble<<<NBt * 16 / 256, 256, 0, stream>>>(feature, P, bufB);
    k_agg<2><<<NBt / 32, 256, 0, stream>>>(bufB, dinv, nullptr, rowptr, csr, b_in,
                                           bufA, nullptr, nullptr);

    for (int i = 0; i < 3; ++i) {
        const f16* bh = BGh + (size_t)i * 4 * 8 * 64 * 8;
        const f16* bl = BGl + (size_t)i * 4 * 8 * 64 * 8;
        const float* ws_i = wsv + (size_t)i * CC;
        const float* wd_i = wdv + (size_t)i * CC;
        const float* gb = gat_b + (size_t)i * CC;
        k_gat_gemm<<<NBt / 32, 256, 0, stream>>>(bufA, bh, bl, ws_i, wd_i, bufB, asrc, adst);
        k_agg<0><<<NBt / 32, 256, 0, stream>>>(bufB, asrc, adst, rowptr, csr, gb,
                                               bufA, nullptr, nullptr);
        k_gat_gemm<<<NBt / 32, 256, 0, stream>>>(bufA, bh, bl, ws_i, wd_i, bufB, asrc, adst);
        if (i < 2) {
            k_agg<1><<<NBt / 32, 256, 0, stream>>>(bufB, asrc, adst, rowptr, csr, gb,
                                                   bufA, nullptr, nullptr);
        } else {
            // last agg: fuse the W_out per-node dot, write pscal only
            k_agg<3><<<NBt / 32, 256, 0, stream>>>(bufB, asrc, adst, rowptr, csr, gb,
                                                   bufA, W_out, pscal);
        }
    }

    k_out_agg<<<NBt / 16, 256, 0, stream>>>(pscal, dinv, rowptr, csr, b_out, gvec);
    k_fc<<<BB, 128, 0, stream>>>(gvec, W_fc1, b_fc1, W_fc2, b_fc2, outp);
}

// Round 19
// 273.599 us; speedup vs baseline: 1.0251x; 1.0251x over previous
//
#include <hip/hip_runtime.h>

// UserGraphNet: B=64 graphs, n=714 nodes, E=16384 edges (+n self loops), C=128.
// Round 18: REVERT to round-16 optimum (4 nodes/wave quarter-wave agg; the 8
// nodes/wave variant regressed: VGPR growth + 8-lane row reads). This is the
// measured best structure: split kernels, f16 features end-to-end, 2-term MFMA
// GEMMs, merged build+prep, table-projection embed, fused W_out dot, XCD swizzle.

#define BB 64
#define NN 714
#define EE 16384
#define ET (EE + NN)          // 17098 edges incl self loops
#define NBt (BB * NN)         // 45696 total nodes
#define CC 128
#define RP (NN + 1)           // rowptr entries per graph
#define DFAST 64              // max degree on the quarter-wave fast path (deg~24)
#define KSP 28                // total padded k-steps across 4 table projections
#define PROJ_ROWS 19021       // 5099 + 400 + 7128 + 6394

typedef _Float16 f16;
typedef __attribute__((ext_vector_type(8))) _Float16 f16x8;
typedef __attribute__((ext_vector_type(4))) _Float16 f16x4;
typedef __attribute__((ext_vector_type(4))) float f32x4;

__device__ __forceinline__ float lrelu01(float x) { return x > 0.f ? x : 0.01f * x; }
__device__ __forceinline__ float lrelu2(float x)  { return x > 0.f ? x : 0.2f  * x; }

__device__ __forceinline__ float wsum(float x) {
#pragma unroll
    for (int o = 32; o > 0; o >>= 1) x += __shfl_xor(x, o);
    return x;
}
// 16-lane (quarter-wave) reductions: xor offsets <=8 stay within the quarter
__device__ __forceinline__ float qsum(float x) {
#pragma unroll
    for (int o = 8; o > 0; o >>= 1) x += __shfl_xor(x, o);
    return x;
}
__device__ __forceinline__ float qmax(float x) {
#pragma unroll
    for (int o = 8; o > 0; o >>= 1) x = fmaxf(x, __shfl_xor(x, o));
    return x;
}

// Bijective XCD swizzle (m204)
__device__ __forceinline__ int xcd_swz(int bid, int nwg) {
    int q = nwg >> 3, r = nwg & 7;
    int x = bid & 7, l = bid >> 3;
    int base = (x < r) ? x * (q + 1) : r * (q + 1) + (x - r) * q;
    return base + l;
}

// ---- merged CSR build (blocks 0..BB-1) + weight prep (blocks BB..) ----
#define NSEG (KSP * 8 * 64)
#define NGAT (3 * 4 * 8 * 64)
#define NPREP (NSEG + NGAT + 3 * CC)
__global__ __launch_bounds__(1024) void k_build_prep(
    const int* __restrict__ edges, int* __restrict__ rowptr,
    int* __restrict__ csr_row, float* __restrict__ dinv,
    const float* __restrict__ W, const float* __restrict__ gat_W,
    const float* __restrict__ a_s, const float* __restrict__ a_d,
    f16* __restrict__ BWh, f16* __restrict__ BWl,
    f16* __restrict__ BGh, f16* __restrict__ BGl,
    float* __restrict__ wsv, float* __restrict__ wdv) {
    __shared__ int degs[NN];
    __shared__ int scan[1024];
    __shared__ int curs[NN];
    int t = threadIdx.x;
    if (blockIdx.x < BB) {
        // ---------------- CSR build ----------------
        int b = blockIdx.x;
        if (t < NN) degs[t] = 0;
        __syncthreads();
        int rr[17], cc[17];
#pragma unroll
        for (int q = 0; q < 17; ++q) {
            int e = q * 1024 + t;
            int r = -1, c = -1;
            if (e < ET) {
                if (e < EE) { r = edges[b * 2 * EE + e]; c = edges[b * 2 * EE + EE + e]; }
                else        { r = c = e - EE; }
                atomicAdd(&degs[c], 1);
            }
            rr[q] = r; cc[q] = c;
        }
        __syncthreads();
        int cnt = (t < NN) ? degs[t] : 0;
        scan[t] = cnt;
        __syncthreads();
        for (int off = 1; off < 1024; off <<= 1) {
            int val = (t >= off) ? scan[t - off] : 0;
            __syncthreads();
            scan[t] += val;
            __syncthreads();
        }
        if (t < NN) {
            rowptr[b * RP + t + 1] = scan[t];
            curs[t] = scan[t] - cnt;                   // exclusive prefix
            dinv[b * NN + t] = cnt > 0 ? rsqrtf((float)cnt) : 0.f;
        }
        if (t == 0) rowptr[b * RP] = 0;
        __syncthreads();
#pragma unroll
        for (int q = 0; q < 17; ++q) {
            if (cc[q] >= 0) {
                int slot = atomicAdd(&curs[cc[q]], 1); // LDS atomic
                csr_row[b * ET + slot] = rr[q];
            }
        }
        return;
    }
    // ---------------- weight prep ----------------
    int idx = (blockIdx.x - BB) * 1024 + t;
    if (idx < NSEG) {
        int lane = idx & 63, tc = idx >> 6;
        int ct = tc & 7, ks = tc >> 3;
        int tt = ks < 10 ? 0 : ks < 14 ? 1 : ks < 21 ? 2 : 3;
        int k0 = tt == 0 ? 0 : tt == 1 ? 10 : tt == 2 ? 14 : 21;
        const int Ktab[4] = {300, 100, 200, 200};
        const int Koff[4] = {0, 300, 400, 600};
        int ksl = ks - k0;
        f16x8 ph, pl;
#pragma unroll
        for (int j = 0; j < 8; ++j) {
            int k = ksl * 32 + (lane >> 4) * 8 + j;
            int c = ct * 16 + (lane & 15);
            float v = (k < Ktab[tt]) ? W[(size_t)(Koff[tt] + k) * CC + c] : 0.f;
            f16 hi = (f16)v;
            ph[j] = hi; pl[j] = (f16)(v - (float)hi);
        }
        *(f16x8*)(BWh + (size_t)idx * 8) = ph;
        *(f16x8*)(BWl + (size_t)idx * 8) = pl;
    } else if (idx < NSEG + NGAT) {
        int i2 = idx - NSEG;
        int lane = i2 & 63, tc = i2 >> 6;
        int ct = tc & 7; tc >>= 3;
        int ks = tc & 3, li = tc >> 2;
        const float* Wl = gat_W + (size_t)li * CC * CC;
        f16x8 ph, pl;
#pragma unroll
        for (int j = 0; j < 8; ++j) {
            int k = ks * 32 + (lane >> 4) * 8 + j;
            int c = ct * 16 + (lane & 15);
            float v = Wl[k * CC + c];
            f16 hi = (f16)v;
            ph[j] = hi; pl[j] = (f16)(v - (float)hi);
        }
        *(f16x8*)(BGh + (size_t)i2 * 8) = ph;
        *(f16x8*)(BGl + (size_t)i2 * 8) = pl;
    } else if (idx < NPREP) {
        int i2 = idx - NSEG - NGAT;
        int i = i2 >> 7, k = i2 & 127;
        const float* Wl = gat_W + (size_t)i * CC * CC;
        float s = 0.f, d = 0.f;
#pragma unroll 4
        for (int c = 0; c < CC; ++c) {
            float w = Wl[k * CC + c];
            s = fmaf(w, a_s[i * CC + c], s);
            d = fmaf(w, a_d[i * CC + c], d);
        }
        wsv[i * CC + k] = s; wdv[i * CC + k] = d;
    }
}

// ---- table-projection GEMM: P[t] = table[t] @ W_in[Koff:Koff+K]  (f32 out) ----
__global__ __launch_bounds__(256) void k_proj(
    const float* __restrict__ poi, const float* __restrict__ cat,
    const float* __restrict__ lat, const float* __restrict__ lon,
    const f16* __restrict__ Bh, const f16* __restrict__ Bl,
    float* __restrict__ P) {
    int bid = blockIdx.x;
    int t, r0;
    if (bid < 160)      { t = 0; r0 = bid * 32; }
    else if (bid < 173) { t = 1; r0 = (bid - 160) * 32; }
    else if (bid < 396) { t = 2; r0 = (bid - 173) * 32; }
    else                { t = 3; r0 = (bid - 396) * 32; }
    const int Ktab[4] = {300, 100, 200, 200};
    const int Rtab[4] = {5099, 400, 7128, 6394};
    const int Rofs[4] = {0, 5099, 5499, 12627};
    const int Kst[4]  = {10, 4, 7, 7};
    const int Bks0[4] = {0, 10, 14, 21};
    const float* tab = t == 0 ? poi : t == 1 ? cat : t == 2 ? lat : lon;
    int K = Ktab[t], R = Rtab[t], nks = Kst[t], bks = Bks0[t];
    int lane = threadIdx.x & 63, w = threadIdx.x >> 6;
    int ct0 = w * 2;
    f32x4 acc[2][2];
#pragma unroll
    for (int rt = 0; rt < 2; ++rt)
#pragma unroll
        for (int c = 0; c < 2; ++c) acc[rt][c] = (f32x4){0.f, 0.f, 0.f, 0.f};

    for (int ks = 0; ks < nks; ++ks) {
        int kbase = ks * 32 + (lane >> 4) * 8;
        f16x8 ah[2], al[2];
#pragma unroll
        for (int rt = 0; rt < 2; ++rt) {
            int row = r0 + rt * 16 + (lane & 15);
            int rowc = row < R ? row : R - 1;
            const float* rp = tab + (size_t)rowc * K;
            float v[8];
            if (kbase + 8 <= K) {
                float4 x0 = ((const float4*)(rp + kbase))[0];
                float4 x1 = ((const float4*)(rp + kbase))[1];
                v[0] = x0.x; v[1] = x0.y; v[2] = x0.z; v[3] = x0.w;
                v[4] = x1.x; v[5] = x1.y; v[6] = x1.z; v[7] = x1.w;
            } else if (kbase >= K) {
#pragma unroll
                for (int m = 0; m < 8; ++m) v[m] = 0.f;
            } else {
#pragma unroll
                for (int m = 0; m < 8; ++m) v[m] = (kbase + m < K) ? rp[kbase + m] : 0.f;
            }
#pragma unroll
            for (int j = 0; j < 8; ++j) {
                f16 hi = (f16)v[j];
                ah[rt][j] = hi; al[rt][j] = (f16)(v[j] - (float)hi);
            }
        }
#pragma unroll
        for (int cti = 0; cti < 2; ++cti) {
            int ct = ct0 + cti;
            f16x8 bh = *(const f16x8*)(Bh + ((size_t)((bks + ks) * 8 + ct) * 64 + lane) * 8);
            f16x8 bl = *(const f16x8*)(Bl + ((size_t)((bks + ks) * 8 + ct) * 64 + lane) * 8);
#pragma unroll
            for (int rt = 0; rt < 2; ++rt) {
                acc[rt][cti] = __builtin_amdgcn_mfma_f32_16x16x32_f16(ah[rt], bh, acc[rt][cti], 0, 0, 0);
                acc[rt][cti] = __builtin_amdgcn_mfma_f32_16x16x32_f16(al[rt], bh, acc[rt][cti], 0, 0, 0);
                acc[rt][cti] = __builtin_amdgcn_mfma_f32_16x16x32_f16(ah[rt], bl, acc[rt][cti], 0, 0, 0);
            }
        }
    }
#pragma unroll
    for (int rt = 0; rt < 2; ++rt)
#pragma unroll
        for (int cti = 0; cti < 2; ++cti)
#pragma unroll
            for (int i = 0; i < 4; ++i) {
                int row = r0 + rt * 16 + (lane >> 4) * 4 + i;
                if (row < R) {
                    int col = (ct0 + cti) * 16 + (lane & 15);
                    P[(size_t)(Rofs[t] + row) * CC + col] = acc[rt][cti][i];
                }
            }
}

// ---- per-node assembly: bufB[g] = P_poi[f0] + P_cat[f1] + P_lat[f3] + P_lon[f4] ----
__global__ __launch_bounds__(256) void k_assemble(
    const int* __restrict__ feature, const float* __restrict__ P,
    f16* __restrict__ out) {
    int tid = xcd_swz(blockIdx.x, gridDim.x) * 256 + threadIdx.x;
    int g = tid >> 4, c8 = (tid & 15) * 8;
    const int* f = feature + (size_t)g * 5;
    const float4* p0 = (const float4*)(P + (size_t)f[0] * CC + c8);
    const float4* p1 = (const float4*)(P + (size_t)(5099 + f[1]) * CC + c8);
    const float4* p2 = (const float4*)(P + (size_t)(5499 + f[3]) * CC + c8);
    const float4* p3 = (const float4*)(P + (size_t)(12627 + f[4]) * CC + c8);
    float4 a0 = p0[0], a1 = p0[1];
    float4 b0 = p1[0], b1 = p1[1];
    float4 c0 = p2[0], c1 = p2[1];
    float4 d0 = p3[0], d1 = p3[1];
    f16x8 r;
    r[0] = (f16)(a0.x + b0.x + c0.x + d0.x);
    r[1] = (f16)(a0.y + b0.y + c0.y + d0.y);
    r[2] = (f16)(a0.z + b0.z + c0.z + d0.z);
    r[3] = (f16)(a0.w + b0.w + c0.w + d0.w);
    r[4] = (f16)(a1.x + b1.x + c1.x + d1.x);
    r[5] = (f16)(a1.y + b1.y + c1.y + d1.y);
    r[6] = (f16)(a1.z + b1.z + c1.z + d1.z);
    r[7] = (f16)(a1.w + b1.w + c1.w + d1.w);
    *(f16x8*)(out + (size_t)g * CC + c8) = r;
}

// ---- GAT gemm, 32-row tile; f16 input (exact A, 2-term MFMA); f16 Hp out ----
__global__ __launch_bounds__(256) void k_gat_gemm(
    const f16* __restrict__ hin, const f16* __restrict__ Bh, const f16* __restrict__ Bl,
    const float* __restrict__ wsv, const float* __restrict__ wdv,
    f16* __restrict__ Hp, float* __restrict__ asrc, float* __restrict__ adst) {
    __shared__ __align__(16) f16 Ah[32 * 128];
    __shared__ float reds[256], redd[256];
    int t = threadIdx.x;
    int g0 = xcd_swz(blockIdx.x, gridDim.x) * 32;
    int lane = t & 63, w = t >> 6;
    int sr = t >> 3, skb = (t & 7) * 16;
    const f16x8* hrow = (const f16x8*)(hin + (size_t)(g0 + sr) * CC + skb);
    f16x8 hv0 = hrow[0], hv1 = hrow[1];
    float ps = 0.f, pd = 0.f;
#pragma unroll
    for (int m = 0; m < 8; ++m) {
        ps = fmaf((float)hv0[m], wsv[skb + m], ps);
        pd = fmaf((float)hv0[m], wdv[skb + m], pd);
        ps = fmaf((float)hv1[m], wsv[skb + 8 + m], ps);
        pd = fmaf((float)hv1[m], wdv[skb + 8 + m], pd);
    }
    {
        int kg0 = (t & 7) * 2;
        int ad0 = sr * 128 + ((kg0 ^ (sr & 7)) << 3);
        int ad1 = sr * 128 + (((kg0 + 1) ^ (sr & 7)) << 3);
        *(f16x8*)&Ah[ad0] = hv0;
        *(f16x8*)&Ah[ad1] = hv1;
    }
    reds[t] = ps; redd[t] = pd;
    __syncthreads();
    if (t < 32) {
        float s = 0.f, d = 0.f;
#pragma unroll
        for (int q = 0; q < 8; ++q) { s += reds[t * 8 + q]; d += redd[t * 8 + q]; }
        asrc[g0 + t] = s; adst[g0 + t] = d;
    }
    f32x4 acc[2][2];
#pragma unroll
    for (int rt = 0; rt < 2; ++rt)
#pragma unroll
        for (int c = 0; c < 2; ++c) acc[rt][c] = (f32x4){0.f, 0.f, 0.f, 0.f};
    int ct0 = w * 2;
#pragma unroll
    for (int ks = 0; ks < 4; ++ks) {
        f16x8 ahf[2];
#pragma unroll
        for (int rt = 0; rt < 2; ++rt) {
            int r = rt * 16 + (lane & 15);
            int kg = (lane >> 4) + ks * 4;
            int ad = r * 128 + ((kg ^ (r & 7)) << 3);
            ahf[rt] = *(const f16x8*)&Ah[ad];
        }
#pragma unroll
        for (int cti = 0; cti < 2; ++cti) {
            int ct = ct0 + cti;
            f16x8 bh = *(const f16x8*)(Bh + ((size_t)(ks * 8 + ct) * 64 + lane) * 8);
            f16x8 bl = *(const f16x8*)(Bl + ((size_t)(ks * 8 + ct) * 64 + lane) * 8);
#pragma unroll
            for (int rt = 0; rt < 2; ++rt) {
                acc[rt][cti] = __builtin_amdgcn_mfma_f32_16x16x32_f16(ahf[rt], bh, acc[rt][cti], 0, 0, 0);
                acc[rt][cti] = __builtin_amdgcn_mfma_f32_16x16x32_f16(ahf[rt], bl, acc[rt][cti], 0, 0, 0);
            }
        }
    }
#pragma unroll
    for (int rt = 0; rt < 2; ++rt)
#pragma unroll
        for (int cti = 0; cti < 2; ++cti)
#pragma unroll
            for (int i = 0; i < 4; ++i) {
                int row = g0 + rt * 16 + (lane >> 4) * 4 + i;
                int col = (ct0 + cti) * 16 + (lane & 15);
                Hp[(size_t)row * CC + col] = (f16)acc[rt][cti][i];
            }
}

// ---- unified aggregate kernel: 4 nodes per wave (16-lane quarter per node) ----
// MODE 0: GAT, out = lrelu01(t)+t. MODE 1: GAT, out = lrelu01(t).
// MODE 2: GCN, out = lrelu01(t). MODE 3: GAT plain, write only pscal = out.Wout.
template <int MODE>
__global__ __launch_bounds__(256) void k_agg(
    const f16* __restrict__ Hp, const float* __restrict__ aux,
    const float* __restrict__ adst, const int* __restrict__ rowptr,
    const int* __restrict__ csr_row, const float* __restrict__ bias,
    f16* __restrict__ out, const float* __restrict__ Wout, float* __restrict__ pscal) {
    __shared__ float2 pr[4][4][DFAST + 2];   // +2 pad: quarters land in distinct banks
    int wid = threadIdx.x >> 6, lane = threadIdx.x & 63;
    int quarter = lane >> 4, ql = lane & 15;
    int g = xcd_swz(blockIdx.x, gridDim.x) * 16 + wid * 4 + quarter;
    int b = g / NN, v = g - b * NN;
    int bN = b * NN, bE = b * ET;
    int s0 = rowptr[b * RP + v], s1 = rowptr[b * RP + v + 1];
    int deg = s1 - s0;

    if (deg <= DFAST) {
        int degp = (deg + 3) & ~3;                 // pad to multiple of 4
        float inv = 1.f;
        // ---- phase 1: <=4 edges/lane in registers, quarter reductions ----
        int rv[4];
        float wv[4];
        if (MODE == 2) {
            float dv = aux[g];
#pragma unroll
            for (int u = 0; u < 4; ++u) {
                int jj = ql + u * 16;
                rv[u] = 0; wv[u] = 0.f;
                if (jj < deg) { rv[u] = csr_row[bE + s0 + jj]; wv[u] = aux[bN + rv[u]] * dv; }
            }
        } else {
            float adv = adst[g];
            float ev[4];
#pragma unroll
            for (int u = 0; u < 4; ++u) {
                int jj = ql + u * 16;
                rv[u] = 0; ev[u] = -3.0e38f;
                if (jj < deg) { rv[u] = csr_row[bE + s0 + jj]; ev[u] = lrelu2(aux[bN + rv[u]] + adv); }
            }
            float m = qmax(fmaxf(fmaxf(ev[0], ev[1]), fmaxf(ev[2], ev[3])));
            float ss = 0.f;
#pragma unroll
            for (int u = 0; u < 4; ++u) {
                wv[u] = __expf(ev[u] - m);          // pads: exp(-inf)=0
                ss += wv[u];
            }
            ss = qsum(ss);
            inv = 1.f / (ss + 1e-16f);              // applied once at the end
        }
#pragma unroll
        for (int u = 0; u < 4; ++u) {
            int jj = ql + u * 16;
            if (jj < degp) pr[wid][quarter][jj] = make_float2(wv[u], __int_as_float(rv[u]));
        }
        // DS pipe is in-order per wave: phase-2 reads see this wave's writes.
        // ---- phase 2: full-row gather per quarter; 4 edges in flight; no shuffles ----
        const f16* Hb = Hp + (size_t)bN * CC;
        float acc0[8], acc1[8], acc2[8], acc3[8];
#pragma unroll
        for (int j = 0; j < 8; ++j) { acc0[j] = 0.f; acc1[j] = 0.f; acc2[j] = 0.f; acc3[j] = 0.f; }
        for (int jj = 0; jj < degp; jj += 4) {
            float2 p0 = pr[wid][quarter][jj];
            float2 p1 = pr[wid][quarter][jj + 1];
            float2 p2 = pr[wid][quarter][jj + 2];
            float2 p3 = pr[wid][quarter][jj + 3];
            f16x8 h0 = *(const f16x8*)(Hb + (size_t)__float_as_int(p0.y) * CC + ql * 8);
            f16x8 h1 = *(const f16x8*)(Hb + (size_t)__float_as_int(p1.y) * CC + ql * 8);
            f16x8 h2 = *(const f16x8*)(Hb + (size_t)__float_as_int(p2.y) * CC + ql * 8);
            f16x8 h3 = *(const f16x8*)(Hb + (size_t)__float_as_int(p3.y) * CC + ql * 8);
#pragma unroll
            for (int j = 0; j < 8; ++j) {
                acc0[j] = fmaf((float)h0[j], p0.x, acc0[j]);
                acc1[j] = fmaf((float)h1[j], p1.x, acc1[j]);
                acc2[j] = fmaf((float)h2[j], p2.x, acc2[j]);
                acc3[j] = fmaf((float)h3[j], p3.x, acc3[j]);
            }
        }
        // ---- epilogue: all 16 lanes live, accumulators lane-local ----
        float sc = (MODE == 2) ? 1.f : inv;
        float4 bb0 = ((const float4*)bias)[ql * 2];
        float4 bb1 = ((const float4*)bias)[ql * 2 + 1];
        float tv[8], ov[8];
#pragma unroll
        for (int j = 0; j < 8; ++j) {
            float x = acc0[j] + acc1[j] + acc2[j] + acc3[j];
            float bv = (j < 4) ? ((const float*)&bb0)[j] : ((const float*)&bb1)[j - 4];
            tv[j] = x * sc + bv;
            float l = lrelu01(tv[j]);
            ov[j] = (MODE == 0) ? l + tv[j] : l;
        }
        if (MODE == 3) {
            // fused out_dot: pscal[g] = ov . Wout
            float4 w0v = ((const float4*)Wout)[ql * 2];
            float4 w1v = ((const float4*)Wout)[ql * 2 + 1];
            float p = ov[0] * w0v.x + ov[1] * w0v.y + ov[2] * w0v.z + ov[3] * w0v.w
                    + ov[4] * w1v.x + ov[5] * w1v.y + ov[6] * w1v.z + ov[7] * w1v.w;
            p = qsum(p);
            if (ql == 0) pscal[g] = p;
        } else {
            f16x8 r;
#pragma unroll
            for (int j = 0; j < 8; ++j) r[j] = (f16)ov[j];
            *(f16x8*)(out + (size_t)g * CC + ql * 8) = r;
        }
        return;
    }
    // ---- fallback deg > DFAST: quarter-wave serial loop; ~never taken ----
    {
        float wsc0 = 0.f;
        float m = 0.f, inv = 1.f, adv = 0.f;
        if (MODE != 2) {
            adv = adst[g];
            m = -3.0e38f;
            for (int j = s0 + ql; j < s1; j += 16)
                m = fmaxf(m, lrelu2(aux[bN + csr_row[bE + j]] + adv));
            m = qmax(m);
            float ssum = 0.f;
            for (int j = s0 + ql; j < s1; j += 16)
                ssum += __expf(lrelu2(aux[bN + csr_row[bE + j]] + adv) - m);
            ssum = qsum(ssum);
            inv = 1.f / (ssum + 1e-16f);
        } else {
            wsc0 = aux[g];
        }
        float acc[8];
#pragma unroll
        for (int j = 0; j < 8; ++j) acc[j] = 0.f;
        for (int j = s0; j < s1; ++j) {
            int r = csr_row[bE + j];
            float wj = (MODE == 2) ? aux[bN + r]
                                   : __expf(lrelu2(aux[bN + r] + adv) - m) * inv;
            f16x8 h = *(const f16x8*)(Hp + (size_t)(bN + r) * CC + ql * 8);
#pragma unroll
            for (int k = 0; k < 8; ++k) acc[k] = fmaf(wj, (float)h[k], acc[k]);
        }
        if (MODE == 2) {
#pragma unroll
            for (int k = 0; k < 8; ++k) acc[k] *= wsc0;
        }
        float4 bb0 = ((const float4*)bias)[ql * 2];
        float4 bb1 = ((const float4*)bias)[ql * 2 + 1];
        float ov[8];
#pragma unroll
        for (int j = 0; j < 8; ++j) {
            float bv = (j < 4) ? ((const float*)&bb0)[j] : ((const float*)&bb1)[j - 4];
            float tvj = acc[j] + bv;
            float l = lrelu01(tvj);
            ov[j] = (MODE == 0) ? l + tvj : l;
        }
        if (MODE == 3) {
            float4 w0v = ((const float4*)Wout)[ql * 2];
            float4 w1v = ((const float4*)Wout)[ql * 2 + 1];
            float p = ov[0] * w0v.x + ov[1] * w0v.y + ov[2] * w0v.z + ov[3] * w0v.w
                    + ov[4] * w1v.x + ov[5] * w1v.y + ov[6] * w1v.z + ov[7] * w1v.w;
            p = qsum(p);
            if (ql == 0) pscal[g] = p;
        } else {
            f16x8 r;
#pragma unroll
            for (int j = 0; j < 8; ++j) r[j] = (f16)ov[j];
            *(f16x8*)(out + (size_t)g * CC + ql * 8) = r;
        }
    }
}

// ---- GCN2 aggregate over scalars: 4 nodes/wave, 16 lanes per node ----
__global__ __launch_bounds__(256) void k_out_agg(
    const float* __restrict__ p, const float* __restrict__ dinv,
    const int* __restrict__ rowptr, const int* __restrict__ csr_row,
    const float* __restrict__ bout, float* __restrict__ gv) {
    int wid = threadIdx.x >> 6, lane = threadIdx.x & 63;
    int quarter = lane >> 4, ql = lane & 15;
    int g = xcd_swz(blockIdx.x, gridDim.x) * 16 + wid * 4 + quarter;
    int b = g / NN, v = g - b * NN;
    int s0 = rowptr[b * RP + v], s1 = rowptr[b * RP + v + 1];
    float acc = 0.f;
    for (int j = s0 + ql; j < s1; j += 16) {
        int r = csr_row[b * ET + j];
        acc += dinv[b * NN + r] * p[b * NN + r];
    }
    acc = qsum(acc);
    if (ql == 0) gv[g] = lrelu01(acc * dinv[g] + bout[0]);
}

__global__ __launch_bounds__(128) void k_fc(
    const float* __restrict__ gv, const float* __restrict__ W1,
    const float* __restrict__ b1, const float* __restrict__ W2,
    const float* __restrict__ b2, float* __restrict__ outp) {
    __shared__ float gs[NN];
    __shared__ float s1[CC];
    int b = blockIdx.x, tx = threadIdx.x;
    for (int v = tx; v < NN; v += 128) gs[v] = gv[b * NN + v];
    __syncthreads();
    float acc = 0.f;
    for (int v = 0; v < NN; ++v) acc = fmaf(gs[v], W1[v * CC + tx], acc);
    float t = lrelu01(acc + b1[tx]);
    s1[tx] = t;
    __syncthreads();
    float acc2 = 0.f;
#pragma unroll
    for (int k = 0; k < CC; ++k) acc2 = fmaf(s1[k], W2[k * CC + tx], acc2);
    outp[b * CC + tx] = acc2 + b2[tx];
}

extern "C" void kernel_launch(void* const* d_in, const int* in_sizes, int n_in,
                              void* d_out, int out_size, void* d_ws, size_t ws_size,
                              hipStream_t stream) {
    const int*   feature  = (const int*)d_in[0];
    const int*   edges    = (const int*)d_in[1];
    const float* poi      = (const float*)d_in[3];
    const float* cat      = (const float*)d_in[4];
    const float* lat      = (const float*)d_in[5];
    const float* lon      = (const float*)d_in[6];
    const float* W_in     = (const float*)d_in[7];
    const float* b_in     = (const float*)d_in[8];
    const float* gat_W    = (const float*)d_in[9];
    const float* gat_asrc = (const float*)d_in[10];
    const float* gat_adst = (const float*)d_in[11];
    const float* gat_b    = (const float*)d_in[12];
    const float* W_out    = (const float*)d_in[13];
    const float* b_out    = (const float*)d_in[14];
    const float* W_fc1    = (const float*)d_in[15];
    const float* b_fc1    = (const float*)d_in[16];
    const float* W_fc2    = (const float*)d_in[17];
    const float* b_fc2    = (const float*)d_in[18];
    float* outp = (float*)d_out;

    char* ws = (char*)d_ws;
    size_t off = 0;
    auto take = [&](size_t bytes) -> char* {
        char* pp = ws + off;
        off = (off + bytes + 255) & ~(size_t)255;
        return pp;
    };
    int*   csr    = (int*)take((size_t)BB * ET * 4);
    int*   rowptr = (int*)take((size_t)BB * RP * 4);
    float* dinv   = (float*)take((size_t)NBt * 4);
    float* asrc   = (float*)take((size_t)NBt * 4);
    float* adst   = (float*)take((size_t)NBt * 4);
    float* pscal  = (float*)take((size_t)NBt * 4);
    float* gvec   = (float*)take((size_t)NBt * 4);
    f16*   bufA   = (f16*)take((size_t)NBt * CC * 2);       // f16 node features
    f16*   bufB   = (f16*)take((size_t)NBt * CC * 2);       // f16 node features
    float* P      = (float*)take((size_t)PROJ_ROWS * CC * 4); // table projections
    f16*   BWh    = (f16*)take((size_t)KSP * 8 * 64 * 8 * 2);
    f16*   BWl    = (f16*)take((size_t)KSP * 8 * 64 * 8 * 2);
    f16*   BGh    = (f16*)take((size_t)3 * 4 * 8 * 64 * 8 * 2);
    f16*   BGl    = (f16*)take((size_t)3 * 4 * 8 * 64 * 8 * 2);
    float* wsv    = (float*)take((size_t)3 * CC * 4);
    float* wdv    = (float*)take((size_t)3 * CC * 4);

    // merged CSR build + weight prep: blocks [0,BB) build, [BB, BB+21) prep
    const int prep_blocks = (NPREP + 1023) / 1024;
    k_build_prep<<<BB + prep_blocks, 1024, 0, stream>>>(
        edges, rowptr, csr, dinv,
        W_in, gat_W, gat_asrc, gat_adst, BWh, BWl, BGh, BGl, wsv, wdv);

    k_proj<<<596, 256, 0, stream>>>(poi, cat, lat, lon, BWh, BWl, P);
    k_assemble<<<NBt * 16 / 256, 256, 0, stream>>>(feature, P, bufB);
    k_agg<2><<<NBt / 16, 256, 0, stream>>>(bufB, dinv, nullptr, rowptr, csr, b_in,
                                           bufA, nullptr, nullptr);

    for (int i = 0; i < 3; ++i) {
        const f16* bh = BGh + (size_t)i * 4 * 8 * 64 * 8;
        const f16* bl = BGl + (size_t)i * 4 * 8 * 64 * 8;
        const float* ws_i = wsv + (size_t)i * CC;
        const float* wd_i = wdv + (size_t)i * CC;
        const float* gb = gat_b + (size_t)i * CC;
        k_gat_gemm<<<NBt / 32, 256, 0, stream>>>(bufA, bh, bl, ws_i, wd_i, bufB, asrc, adst);
        k_agg<0><<<NBt / 16, 256, 0, stream>>>(bufB, asrc, adst, rowptr, csr, gb,
                                               bufA, nullptr, nullptr);
        k_gat_gemm<<<NBt / 32, 256, 0, stream>>>(bufA, bh, bl, ws_i, wd_i, bufB, asrc, adst);
        if (i < 2) {
            k_agg<1><<<NBt / 16, 256, 0, stream>>>(bufB, asrc, adst, rowptr, csr, gb,
                                                   bufA, nullptr, nullptr);
        } else {
            // last agg: fuse the W_out per-node dot, write pscal only
            k_agg<3><<<NBt / 16, 256, 0, stream>>>(bufB, asrc, adst, rowptr, csr, gb,
                                                   bufA, W_out, pscal);
        }
    }

    k_out_agg<<<NBt / 16, 256, 0, stream>>>(pscal, dinv, rowptr, csr, b_out, gvec);
    k_fc<<<BB, 128, 0, stream>>>(gvec, W_fc1, b_fc1, W_fc2, b_fc2, outp);
}